// Round 1
// baseline (198.926 us; speedup 1.0000x reference)
//
#include <hip/hip_runtime.h>
#include <math.h>
#include <stdint.h>

// Problem constants (static per reference):
//   B=32, N_ATOMS=128, C=25 (rep 2,2,0), RADIUS=8, MAX_NEIGHBORS=32
#define NATOMS   128
#define NCELLS   25
#define NCAND    (NATOMS * NCELLS)   // 3200 candidates per center atom
#define MAXNB    32
#define R2       64.0f
#define BLK      256

// One block per (b, i) center atom. Computes d2 for all 3200 (j, c)
// candidates, finds the exact 32-NN cutoff key (stable tie-break on flat
// index, matching jnp stable argsort), writes the three big outputs, and
// stores min(count_within, 32) per center into ws for a later reduction.
__global__ __launch_bounds__(BLK) void graph_kernel(
    const float* __restrict__ pos, const float* __restrict__ cell,
    float* __restrict__ out_dist, float* __restrict__ out_ctype,
    float* __restrict__ out_mask, float* __restrict__ ws_counts)
{
    __shared__ float s_pos[NATOMS * 3];
    __shared__ float s_ctr[3];
    __shared__ float s_off[NCELLS * 3];
    __shared__ float s_d2[NCAND];                 // masked: inf if not within
    __shared__ unsigned s_hist[256];
    __shared__ unsigned long long s_binkeys[NCAND];
    __shared__ unsigned s_cnt;
    __shared__ int s_binsel;
    __shared__ int s_need;
    __shared__ unsigned long long s_K;
    __shared__ int s_wred[4];

    const int bi  = blockIdx.x;        // b*128 + i
    const int b   = bi >> 7;
    const int tid = threadIdx.x;

    // ---- stage inputs into LDS ----
    for (int t = tid; t < NATOMS * 3; t += BLK)
        s_pos[t] = pos[b * (NATOMS * 3) + t];
    if (tid < 3) s_ctr[tid] = pos[bi * 3 + tid];
    if (tid < NCELLS * 3) {
        int c = tid / 3, k = tid - c * 3;
        // u = (ux, uy, 0), c = (ux+2)*5 + (uy+2)
        float ux = (float)(c / 5 - 2);
        float uy = (float)(c % 5 - 2);
        float c0 = cell[b * 9 + 0 + k];
        float c1 = cell[b * 9 + 3 + k];
        // off = ux*cell_row0 + uy*cell_row1 (+0*cell_row2, exact no-op).
        // Products are exact (|u|<=2), single rounding on the add -> matches
        // any summation order the reference einsum used.
        s_off[tid] = __fadd_rn(__fmul_rn(ux, c0), __fmul_rn(uy, c1));
    }
    s_hist[tid] = 0;   // BLK == 256 bins
    if (tid == 0) { s_cnt = 0; s_binsel = -1; s_K = ~0ULL; }
    __syncthreads();

    // ---- pass 1: d2, within mask, histogram ----
    int local = 0;
    for (int f = tid; f < NCAND; f += BLK) {
        int j = f / NCELLS;
        int c = f - j * NCELLS;
        // Replicate reference association exactly, no FMA contraction:
        // dv = (pos_j - pos_i) + off ; d2 = (dx*dx + dy*dy) + dz*dz
        float dx = __fadd_rn(__fsub_rn(s_pos[j*3+0], s_ctr[0]), s_off[c*3+0]);
        float dy = __fadd_rn(__fsub_rn(s_pos[j*3+1], s_ctr[1]), s_off[c*3+1]);
        float dz = __fadd_rn(__fsub_rn(s_pos[j*3+2], s_ctr[2]), s_off[c*3+2]);
        float d2 = __fadd_rn(__fadd_rn(__fmul_rn(dx,dx), __fmul_rn(dy,dy)),
                             __fmul_rn(dz,dz));
        bool within = (d2 <= R2) && (d2 > 1e-4f);
        s_d2[f] = within ? d2 : __builtin_inff();
        if (within) {
            local++;
            int bin = (int)(d2 * 4.0f);     // bins of width 0.25 over [0,64]
            if (bin > 255) bin = 255;
            atomicAdd(&s_hist[bin], 1u);
        }
    }

    // ---- block-reduce within count ----
    for (int o = 32; o; o >>= 1) local += __shfl_down(local, o);
    if ((tid & 63) == 0) s_wred[tid >> 6] = local;
    __syncthreads();
    if (tid == 0) {
        int tot = s_wred[0] + s_wred[1] + s_wred[2] + s_wred[3];
        ws_counts[bi] = (float)(tot < MAXNB ? tot : MAXNB);
        if (tot > MAXNB) {
            int cum = 0;
            for (int bn = 0; bn < 256; bn++) {
                int h = (int)s_hist[bn];
                if (cum + h >= MAXNB) { s_binsel = bn; s_need = MAXNB - cum; break; }
                cum += h;
            }
        }
    }
    __syncthreads();

    // ---- pass 2: exact cutoff key inside the critical bin ----
    const int binsel = s_binsel;
    if (binsel >= 0) {
        for (int f = tid; f < NCAND; f += BLK) {
            float d2 = s_d2[f];
            if (d2 <= R2) {
                int bin = (int)(d2 * 4.0f);
                if (bin > 255) bin = 255;
                if (bin == binsel) {
                    unsigned idx = atomicAdd(&s_cnt, 1u);
                    s_binkeys[idx] = ((unsigned long long)__float_as_uint(d2) << 32)
                                     | (unsigned)f;
                }
            }
        }
        __syncthreads();
        int m = (int)s_cnt;
        int need = s_need;
        for (int p = tid; p < m; p += BLK) {
            unsigned long long kp = s_binkeys[p];
            int r = 0;
            for (int q = 0; q < m; q++) r += (s_binkeys[q] < kp);
            if (r == need - 1) s_K = kp;    // unique: keys are distinct
        }
        __syncthreads();
    }
    const unsigned long long K = s_K;

    // ---- write outputs (float4, coalesced) ----
    const long long base = (long long)bi * NCAND;
    float4* o0 = (float4*)(out_dist  + base);
    float4* o1 = (float4*)(out_ctype + base);
    float4* o2 = (float4*)(out_mask  + base);
    for (int v = tid; v < NCAND / 4; v += BLK) {
        float4 dq = ((const float4*)s_d2)[v];
        float d[4] = {dq.x, dq.y, dq.z, dq.w};
        float4 r0, r1, r2;
        float* p0 = &r0.x; float* p1 = &r1.x; float* p2 = &r2.x;
        #pragma unroll
        for (int e = 0; e < 4; e++) {
            int f = v * 4 + e;
            float d2 = d[e];
            bool within = (d2 <= R2);       // inf for non-within reconstructs mask
            unsigned long long key =
                ((unsigned long long)__float_as_uint(d2) << 32) | (unsigned)f;
            bool keep = within && (key <= K);
            int c = f % NCELLS;
            // ct = (ux+2)*5 + (uy+2)*5 (mults=[5,5,1] per reference/torch code)
            p0[e] = keep ? sqrtf(d2) : 0.0f;
            p1[e] = keep ? (float)(5 * (c / 5) + 5 * (c % 5)) : 0.0f;
            p2[e] = keep ? 1.0f : 0.0f;
        }
        o0[v] = r0; o1[v] = r1; o2[v] = r2;
    }
}

// Reduce per-center clamped counts -> per-image totals. Counts are small
// integers; float accumulation is exact (< 2^24).
__global__ __launch_bounds__(64) void reduce_counts(
    const float* __restrict__ ws_counts, float* __restrict__ out_nb)
{
    int b = blockIdx.x;
    int t = threadIdx.x;    // 64 threads
    float v = ws_counts[b * NATOMS + t] + ws_counts[b * NATOMS + 64 + t];
    for (int o = 32; o; o >>= 1) v += __shfl_down(v, o);
    if (t == 0) out_nb[b] = v;
}

extern "C" void kernel_launch(void* const* d_in, const int* in_sizes, int n_in,
                              void* d_out, int out_size, void* d_ws, size_t ws_size,
                              hipStream_t stream) {
    const float* pos  = (const float*)d_in[0];   // [32,128,3]
    const float* cell = (const float*)d_in[1];   // [32,3,3]
    float* out = (float*)d_out;
    const long long E = 32LL * NATOMS * NATOMS * NCELLS;   // 13,107,200
    float* out_dist  = out;
    float* out_ct    = out + E;
    float* out_mask  = out + 2 * E;
    float* out_nb    = out + 3 * E;                         // 32 floats
    float* ws = (float*)d_ws;                               // 4096 floats

    hipLaunchKernelGGL(graph_kernel, dim3(32 * NATOMS), dim3(BLK), 0, stream,
                       pos, cell, out_dist, out_ct, out_mask, ws);
    hipLaunchKernelGGL(reduce_counts, dim3(32), dim3(64), 0, stream,
                       ws, out_nb);
}

// Round 2
// 170.247 us; speedup vs baseline: 1.1685x; 1.1685x over previous
//
#include <hip/hip_runtime.h>
#include <math.h>
#include <stdint.h>

// Problem constants (static per reference):
//   B=32, N_ATOMS=128, C=25 (rep 2,2,0), RADIUS=8, MAX_NEIGHBORS=32
#define NATOMS   128
#define NCELLS   25
#define NCAND    (NATOMS * NCELLS)   // 3200 candidates per center atom
#define MAXNB    32
#define R2       64.0f
#define BLK      256
#define KEYCAP   256                 // critical-bin key buffer (expected ~6 used)

// One block per (b, i) center atom. LDS budget ~19 KB -> 8 blocks/CU (full
// 32-wave occupancy). Selection: 256-bin d2 histogram + parallel prefix scan
// finds the bin containing the 32nd-nearest candidate; exact stable cutoff key
// (d2 bits << 32 | flat idx, matching jnp stable argsort tie-break) found among
// that bin's members.
__global__ __launch_bounds__(BLK) void graph_kernel(
    const float* __restrict__ pos, const float* __restrict__ cell,
    float* __restrict__ out_dist, float* __restrict__ out_ctype,
    float* __restrict__ out_mask, float* __restrict__ ws_counts)
{
    __shared__ float s_pos[NATOMS * 3];
    __shared__ float s_ctr[3];
    __shared__ float s_off[NCELLS * 3];
    __shared__ float s_d2[NCAND];                 // inf where not within
    __shared__ unsigned s_hist[256];
    __shared__ unsigned s_scan[256];
    __shared__ unsigned long long s_keys[KEYCAP];
    __shared__ unsigned s_cnt;
    __shared__ int s_binsel;
    __shared__ int s_need;
    __shared__ unsigned long long s_K;

    const int bi  = blockIdx.x;        // b*128 + i
    const int b   = bi >> 7;
    const int tid = threadIdx.x;

    // ---- stage inputs into LDS ----
    for (int t = tid; t < NATOMS * 3; t += BLK)
        s_pos[t] = pos[b * (NATOMS * 3) + t];
    if (tid < 3) s_ctr[tid] = pos[bi * 3 + tid];
    if (tid < NCELLS * 3) {
        int c = tid / 3, k = tid - c * 3;
        float ux = (float)(c / 5 - 2);
        float uy = (float)(c % 5 - 2);
        float c0 = cell[b * 9 + 0 + k];
        float c1 = cell[b * 9 + 3 + k];
        // off = ux*row0 + uy*row1; products exact (|u|<=2), one rounded add.
        s_off[tid] = __fadd_rn(__fmul_rn(ux, c0), __fmul_rn(uy, c1));
    }
    s_hist[tid] = 0;
    if (tid == 0) { s_cnt = 0; s_binsel = -1; s_need = 0; s_K = ~0ULL; }
    __syncthreads();

    // ---- pass 1: d2, within mask, histogram ----
    for (int f = tid; f < NCAND; f += BLK) {
        int j = f / NCELLS;
        int c = f - j * NCELLS;
        // Replicate reference association exactly (no FMA contraction):
        // dv = (pos_j - pos_i) + off ; d2 = (dx*dx + dy*dy) + dz*dz
        float dx = __fadd_rn(__fsub_rn(s_pos[j*3+0], s_ctr[0]), s_off[c*3+0]);
        float dy = __fadd_rn(__fsub_rn(s_pos[j*3+1], s_ctr[1]), s_off[c*3+1]);
        float dz = __fadd_rn(__fsub_rn(s_pos[j*3+2], s_ctr[2]), s_off[c*3+2]);
        float d2 = __fadd_rn(__fadd_rn(__fmul_rn(dx,dx), __fmul_rn(dy,dy)),
                             __fmul_rn(dz,dz));
        bool within = (d2 <= R2) && (d2 > 1e-4f);
        s_d2[f] = within ? d2 : __builtin_inff();
        if (within) {
            int bin = (int)(d2 * 4.0f);     // width-0.25 bins over [0,64]
            if (bin > 255) bin = 255;
            atomicAdd(&s_hist[bin], 1u);
        }
    }
    __syncthreads();

    // ---- parallel inclusive prefix scan of the histogram (Hillis-Steele) ----
    const unsigned h = s_hist[tid];
    s_scan[tid] = h;
    __syncthreads();
    #pragma unroll
    for (int off = 1; off < 256; off <<= 1) {
        unsigned v = s_scan[tid];
        unsigned add = (tid >= off) ? s_scan[tid - off] : 0u;
        __syncthreads();
        s_scan[tid] = v + add;
        __syncthreads();
    }
    const unsigned cum_incl = s_scan[tid];
    const unsigned cum_excl = cum_incl - h;
    if (tid == 255) {
        int tot = (int)cum_incl;
        ws_counts[bi] = (float)(tot < MAXNB ? tot : MAXNB);
    }
    // Bin containing the rank-(MAXNB-1) candidate (if >= MAXNB exist).
    if (h > 0 && cum_excl < MAXNB && cum_incl >= MAXNB) {
        s_binsel = tid;
        s_need   = MAXNB - (int)cum_excl;
    }
    __syncthreads();

    // ---- pass 2: exact cutoff key inside the critical bin ----
    const int binsel = s_binsel;
    if (binsel >= 0) {
        for (int f = tid; f < NCAND; f += BLK) {
            float d2 = s_d2[f];
            if (d2 <= R2) {
                int bin = (int)(d2 * 4.0f);
                if (bin > 255) bin = 255;
                if (bin == binsel) {
                    unsigned idx = atomicAdd(&s_cnt, 1u);
                    if (idx < KEYCAP)
                        s_keys[idx] = ((unsigned long long)__float_as_uint(d2) << 32)
                                      | (unsigned)f;
                }
            }
        }
        __syncthreads();
        const int m = (int)s_cnt;
        const int need = s_need;
        if (m <= KEYCAP) {
            for (int p = tid; p < m; p += BLK) {
                unsigned long long kp = s_keys[p];
                int r = 0;
                for (int q = 0; q < m; q++) r += (s_keys[q] < kp);
                if (r == need - 1) s_K = kp;   // keys distinct -> unique
            }
        } else {
            // Robust fallback (never expected): rank by rescanning s_d2.
            for (int f = tid; f < NCAND; f += BLK) {
                float d2 = s_d2[f];
                if (d2 <= R2) {
                    int bin = (int)(d2 * 4.0f);
                    if (bin > 255) bin = 255;
                    if (bin == binsel) {
                        unsigned long long kf =
                            ((unsigned long long)__float_as_uint(d2) << 32) | (unsigned)f;
                        int r = 0;
                        for (int q = 0; q < NCAND; q++) {
                            float dq = s_d2[q];
                            if (dq <= R2) {
                                int bq = (int)(dq * 4.0f);
                                if (bq > 255) bq = 255;
                                if (bq == binsel) {
                                    unsigned long long kq =
                                        ((unsigned long long)__float_as_uint(dq) << 32)
                                        | (unsigned)q;
                                    r += (kq < kf);
                                }
                            }
                        }
                        if (r == need - 1) s_K = kf;
                    }
                }
            }
        }
        __syncthreads();
    }
    const unsigned long long K = s_K;

    // ---- write outputs (float4, coalesced) ----
    const long long base = (long long)bi * NCAND;
    float4* o0 = (float4*)(out_dist  + base);
    float4* o1 = (float4*)(out_ctype + base);
    float4* o2 = (float4*)(out_mask  + base);
    for (int v = tid; v < NCAND / 4; v += BLK) {
        float4 dq = ((const float4*)s_d2)[v];
        float d[4] = {dq.x, dq.y, dq.z, dq.w};
        float4 r0, r1, r2;
        float* p0 = &r0.x; float* p1 = &r1.x; float* p2 = &r2.x;
        #pragma unroll
        for (int e = 0; e < 4; e++) {
            int f = v * 4 + e;
            float d2 = d[e];
            bool within = (d2 <= R2);       // inf for non-within reconstructs mask
            unsigned long long key =
                ((unsigned long long)__float_as_uint(d2) << 32) | (unsigned)f;
            bool keep = within && (key <= K);
            int c = f % NCELLS;
            // ct = (ux+2)*5 + (uy+2)*5 (mults=[5,5,1] quirk per reference)
            p0[e] = keep ? sqrtf(d2) : 0.0f;
            p1[e] = keep ? (float)(5 * (c / 5) + 5 * (c % 5)) : 0.0f;
            p2[e] = keep ? 1.0f : 0.0f;
        }
        o0[v] = r0; o1[v] = r1; o2[v] = r2;
    }
}

// Reduce per-center clamped counts -> per-image totals (exact in f32).
__global__ __launch_bounds__(64) void reduce_counts(
    const float* __restrict__ ws_counts, float* __restrict__ out_nb)
{
    int b = blockIdx.x;
    int t = threadIdx.x;    // 64 threads
    float v = ws_counts[b * NATOMS + t] + ws_counts[b * NATOMS + 64 + t];
    for (int o = 32; o; o >>= 1) v += __shfl_down(v, o);
    if (t == 0) out_nb[b] = v;
}

extern "C" void kernel_launch(void* const* d_in, const int* in_sizes, int n_in,
                              void* d_out, int out_size, void* d_ws, size_t ws_size,
                              hipStream_t stream) {
    const float* pos  = (const float*)d_in[0];   // [32,128,3]
    const float* cell = (const float*)d_in[1];   // [32,3,3]
    float* out = (float*)d_out;
    const long long E = 32LL * NATOMS * NATOMS * NCELLS;   // 13,107,200
    float* out_dist  = out;
    float* out_ct    = out + E;
    float* out_mask  = out + 2 * E;
    float* out_nb    = out + 3 * E;                         // 32 floats
    float* ws = (float*)d_ws;                               // 4096 floats

    hipLaunchKernelGGL(graph_kernel, dim3(32 * NATOMS), dim3(BLK), 0, stream,
                       pos, cell, out_dist, out_ct, out_mask, ws);
    hipLaunchKernelGGL(reduce_counts, dim3(32), dim3(64), 0, stream,
                       ws, out_nb);
}

// Round 3
// 167.881 us; speedup vs baseline: 1.1849x; 1.0141x over previous
//
#include <hip/hip_runtime.h>
#include <math.h>
#include <stdint.h>

// Problem constants (static per reference):
//   B=32, N_ATOMS=128, C=25 (rep 2,2,0), RADIUS=8, MAX_NEIGHBORS=32
#define NATOMS   128
#define NCELLS   25
#define NCAND    (NATOMS * NCELLS)   // 3200 candidates per center atom
#define MAXNB    32
#define R2       64.0f
#define BLK      256
#define KEYCAP   128

// One block per (b, i) center atom. ~17.5 KB LDS -> 8 blocks/CU (full 32-wave
// occupancy). Selection: fine histogram over d2 in [0,16) (the 32nd neighbor
// sits at d2 ~ 2.5 at this density; ~6x fewer LDS atomics than full-range),
// wave-shuffle prefix scan (2 barriers), exact stable cutoff key
// (d2 bits << 32 | flat idx) among the critical bin's members. Full-range
// histogram retry if <32 candidates fall below d2=16 (robustness; not expected).
__global__ __launch_bounds__(BLK) void graph_kernel(
    const float* __restrict__ pos, const float* __restrict__ cell,
    float* __restrict__ out_dist, float* __restrict__ out_ctype,
    float* __restrict__ out_mask, float* __restrict__ ws_counts)
{
    __shared__ float4 s_pos4[NATOMS];          // padded: 1 ds_read_b128 per j
    __shared__ float4 s_off4[NCELLS];          // wave-uniform broadcast per c
    __shared__ float  s_ct[NCELLS];            // ctype LUT
    __shared__ float  s_ctr[3];
    __shared__ float  s_d2[NCAND];             // inf where not within
    __shared__ unsigned s_hist[256];
    __shared__ unsigned s_wtot[4];
    __shared__ int s_wred[4];
    __shared__ unsigned long long s_keys[KEYCAP];
    __shared__ unsigned s_cnt;
    __shared__ int s_binsel, s_need, s_tot, s_att;
    __shared__ unsigned long long s_K;

    const int bi   = blockIdx.x;       // b*128 + i
    const int b    = bi >> 7;
    const int tid  = threadIdx.x;
    const int lane = tid & 63;
    const int w    = tid >> 6;

    // ---- stage inputs into LDS (disjoint thread ranges) ----
    if (tid < NATOMS) {
        const float* p = pos + (b * NATOMS + tid) * 3;
        s_pos4[tid] = make_float4(p[0], p[1], p[2], 0.0f);
    }
    if (tid >= NATOMS && tid < NATOMS + 3)
        s_ctr[tid - NATOMS] = pos[bi * 3 + (tid - NATOMS)];
    if (tid >= 160 && tid < 160 + NCELLS) {
        int c = tid - 160;
        float ux = (float)(c / 5 - 2);
        float uy = (float)(c % 5 - 2);
        // off = ux*row0 + uy*row1; products exact (|u|<=2), one rounded add.
        float ox = __fadd_rn(__fmul_rn(ux, cell[b*9+0]), __fmul_rn(uy, cell[b*9+3]));
        float oy = __fadd_rn(__fmul_rn(ux, cell[b*9+1]), __fmul_rn(uy, cell[b*9+4]));
        float oz = __fadd_rn(__fmul_rn(ux, cell[b*9+2]), __fmul_rn(uy, cell[b*9+5]));
        s_off4[c] = make_float4(ox, oy, oz, 0.0f);
        // ct = (ux+2)*5 + (uy+2)*5 (mults=[5,5,1] quirk per reference)
        s_ct[c] = (float)(5 * (c / 5) + 5 * (c % 5));
    }
    s_hist[tid] = 0u;
    if (tid == 0) { s_cnt = 0; s_binsel = -1; s_need = 0; s_att = 0; s_K = ~0ULL; }
    __syncthreads();

    const float cx = s_ctr[0], cy = s_ctr[1], cz = s_ctr[2];

    // ---- pass 1: d2, within count, fine histogram (d2 < 16 only) ----
    int local = 0;
    for (int g = tid; g < NCAND; g += BLK) {
        int c = g >> 7;            // wave-uniform within an iteration
        int j = g & 127;
        float4 p = s_pos4[j];
        float4 o = s_off4[c];
        // Replicate reference association exactly (no FMA contraction):
        float dx = __fadd_rn(__fsub_rn(p.x, cx), o.x);
        float dy = __fadd_rn(__fsub_rn(p.y, cy), o.y);
        float dz = __fadd_rn(__fsub_rn(p.z, cz), o.z);
        float d2 = __fadd_rn(__fadd_rn(__fmul_rn(dx,dx), __fmul_rn(dy,dy)),
                             __fmul_rn(dz,dz));
        bool within = (d2 <= R2) && (d2 > 1e-4f);
        int f = j * NCELLS + c;    // reference flat layout; odd stride: no conflicts
        s_d2[f] = within ? d2 : __builtin_inff();
        if (within) {
            local++;
            if (d2 < 16.0f)
                atomicAdd(&s_hist[(int)(d2 * 16.0f)], 1u);
        }
    }
    for (int o = 32; o; o >>= 1) local += __shfl_down(local, o);
    if (lane == 0) s_wred[w] = local;
    __syncthreads();
    if (tid == 0) {
        int tot = s_wred[0] + s_wred[1] + s_wred[2] + s_wred[3];
        s_tot = tot;
        ws_counts[bi] = (float)(tot < MAXNB ? tot : MAXNB);
    }
    __syncthreads();

    if (s_tot > MAXNB) {
        // ---- find critical bin: attempt 0 = [0,16) (prebuilt), attempt 1 = full ----
        for (int att = 0; att < 2 && s_binsel < 0; att++) {
            if (att == 1) {   // rebuild full-range histogram (rare path)
                s_hist[tid] = 0u;
                __syncthreads();
                for (int v = tid; v < NCAND / 4; v += BLK) {
                    float4 dq = ((const float4*)s_d2)[v];
                    #pragma unroll
                    for (int e = 0; e < 4; e++) {
                        float d2 = (&dq.x)[e];
                        if (d2 < 64.5f) {
                            int bin = (int)(d2 * 4.0f);
                            if (bin > 255) bin = 255;
                            atomicAdd(&s_hist[bin], 1u);
                        }
                    }
                }
                __syncthreads();
            }
            // wave-shuffle inclusive scan of 256 bins (4 waves x 64 bins)
            unsigned h = s_hist[tid];
            int v = (int)h;
            #pragma unroll
            for (int off = 1; off < 64; off <<= 1) {
                int u = __shfl_up(v, off, 64);
                if (lane >= off) v += u;
            }
            if (lane == 63) s_wtot[w] = (unsigned)v;
            __syncthreads();
            unsigned pre = 0;
            for (int ww = 0; ww < w; ww++) pre += s_wtot[ww];
            unsigned htot = s_wtot[0] + s_wtot[1] + s_wtot[2] + s_wtot[3];
            unsigned ci = (unsigned)v + pre, ce = ci - h;
            if (htot >= MAXNB && h > 0 && ce < MAXNB && ci >= MAXNB) {
                s_binsel = tid;
                s_need   = MAXNB - (int)ce;
                s_att    = att;
            }
            __syncthreads();
        }

        // ---- exact cutoff key inside the critical bin ----
        const int   binsel = s_binsel;
        const float sc  = s_att ? 4.0f  : 16.0f;
        const float lim = s_att ? 64.5f : 16.0f;
        for (int v = tid; v < NCAND / 4; v += BLK) {
            float4 dq = ((const float4*)s_d2)[v];
            #pragma unroll
            for (int e = 0; e < 4; e++) {
                float d2 = (&dq.x)[e];
                if (d2 < lim) {
                    int bin = (int)(d2 * sc);
                    if (bin > 255) bin = 255;
                    if (bin == binsel) {
                        unsigned idx = atomicAdd(&s_cnt, 1u);
                        if (idx < KEYCAP)
                            s_keys[idx] =
                                ((unsigned long long)__float_as_uint(d2) << 32)
                                | (unsigned)(v * 4 + e);
                    }
                }
            }
        }
        __syncthreads();
        const int m = (int)s_cnt, need = s_need;
        if (m <= KEYCAP) {
            for (int p = tid; p < m; p += BLK) {
                unsigned long long kp = s_keys[p];
                int r = 0;
                for (int q = 0; q < m; q++) r += (s_keys[q] < kp);
                if (r == need - 1) s_K = kp;   // keys distinct -> unique
            }
        } else {
            // Robust fallback (never expected): rank by rescanning s_d2.
            for (int f = tid; f < NCAND; f += BLK) {
                float d2 = s_d2[f];
                if (d2 < lim) {
                    int bin = (int)(d2 * sc);
                    if (bin > 255) bin = 255;
                    if (bin == binsel) {
                        unsigned long long kf =
                            ((unsigned long long)__float_as_uint(d2) << 32) | (unsigned)f;
                        int r = 0;
                        for (int q = 0; q < NCAND; q++) {
                            float dq = s_d2[q];
                            if (dq < lim) {
                                int bq = (int)(dq * sc);
                                if (bq > 255) bq = 255;
                                if (bq == binsel) {
                                    unsigned long long kq =
                                        ((unsigned long long)__float_as_uint(dq) << 32)
                                        | (unsigned)q;
                                    r += (kq < kf);
                                }
                            }
                        }
                        if (r == need - 1) s_K = kf;
                    }
                }
            }
        }
        __syncthreads();
    }
    const unsigned long long K = s_K;

    // ---- write outputs (float4, coalesced) ----
    const long long base = (long long)bi * NCAND;
    float4* o0 = (float4*)(out_dist  + base);
    float4* o1 = (float4*)(out_ctype + base);
    float4* o2 = (float4*)(out_mask  + base);
    for (int v = tid; v < NCAND / 4; v += BLK) {
        float4 dq = ((const float4*)s_d2)[v];
        int f0 = v * 4;
        int c0 = f0 % NCELLS;      // one magic-div per 4 candidates
        float4 r0, r1, r2;
        #pragma unroll
        for (int e = 0; e < 4; e++) {
            float d2 = (&dq.x)[e];
            int ce = c0 + e; if (ce >= NCELLS) ce -= NCELLS;
            bool within = (d2 <= R2);   // inf for non-within reconstructs mask
            unsigned long long key =
                ((unsigned long long)__float_as_uint(d2) << 32) | (unsigned)(f0 + e);
            bool keep = within && (key <= K);
            (&r0.x)[e] = keep ? sqrtf(d2) : 0.0f;
            (&r1.x)[e] = keep ? s_ct[ce] : 0.0f;
            (&r2.x)[e] = keep ? 1.0f : 0.0f;
        }
        o0[v] = r0; o1[v] = r1; o2[v] = r2;
    }
}

// Reduce per-center clamped counts -> per-image totals (exact in f32).
__global__ __launch_bounds__(64) void reduce_counts(
    const float* __restrict__ ws_counts, float* __restrict__ out_nb)
{
    int b = blockIdx.x;
    int t = threadIdx.x;    // 64 threads
    float v = ws_counts[b * NATOMS + t] + ws_counts[b * NATOMS + 64 + t];
    for (int o = 32; o; o >>= 1) v += __shfl_down(v, o);
    if (t == 0) out_nb[b] = v;
}

extern "C" void kernel_launch(void* const* d_in, const int* in_sizes, int n_in,
                              void* d_out, int out_size, void* d_ws, size_t ws_size,
                              hipStream_t stream) {
    const float* pos  = (const float*)d_in[0];   // [32,128,3]
    const float* cell = (const float*)d_in[1];   // [32,3,3]
    float* out = (float*)d_out;
    const long long E = 32LL * NATOMS * NATOMS * NCELLS;   // 13,107,200
    float* out_dist  = out;
    float* out_ct    = out + E;
    float* out_mask  = out + 2 * E;
    float* out_nb    = out + 3 * E;                         // 32 floats
    float* ws = (float*)d_ws;                               // 4096 floats

    hipLaunchKernelGGL(graph_kernel, dim3(32 * NATOMS), dim3(BLK), 0, stream,
                       pos, cell, out_dist, out_ct, out_mask, ws);
    hipLaunchKernelGGL(reduce_counts, dim3(32), dim3(64), 0, stream,
                       ws, out_nb);
}